// Round 1
// baseline (7661.886 us; speedup 1.0000x reference)
//
#include <hip/hip_runtime.h>
#include <math.h>

#define B_ 32
#define C_ 3
#define IMG_ 224
#define P_ 32
#define G_ 7
#define NPATCH 49
#define E_ 768
#define NH_ 12
#define L_ 12
#define DH_ 64
#define DFF_ 3072
#define MLP_ 2048
#define NC_ 5
#define TOK 62
#define MROWS (B_*TOK)      // 1984
#define FLAT_ (TOK*E_)      // 47616

// ---------------- generic fp32 GEMM: C[m,n] = act(sum_k A[m,k]*W[n,k] + bias[n]) ----------------
// A: M x K row-major.  W: N x K row-major.  N % 64 == 0, K % 16 == 0.  M guarded.
__global__ __launch_bounds__(256) void gemm_bias_kernel(
    const float* __restrict__ A, const float* __restrict__ W,
    const float* __restrict__ bias, float* __restrict__ C,
    int M, int N, int K, int act)
{
    __shared__ float As[16][68];
    __shared__ float Ws[16][68];
    int tid = threadIdx.x;
    int tx = tid & 15, ty = tid >> 4;
    int m0 = blockIdx.y * 64, n0 = blockIdx.x * 64;
    float acc[4][4] = {};
    int lr = tid >> 2;            // 0..63
    int lc = (tid & 3) * 4;       // 0,4,8,12

    for (int k0 = 0; k0 < K; k0 += 16) {
        // stage A tile (transposed to [k][m]) and W tile ([k][n])
        float4 va = make_float4(0.f, 0.f, 0.f, 0.f);
        int m = m0 + lr;
        if (m < M) va = *reinterpret_cast<const float4*>(&A[(size_t)m * K + k0 + lc]);
        As[lc + 0][lr] = va.x; As[lc + 1][lr] = va.y; As[lc + 2][lr] = va.z; As[lc + 3][lr] = va.w;
        float4 vw = *reinterpret_cast<const float4*>(&W[(size_t)(n0 + lr) * K + k0 + lc]);
        Ws[lc + 0][lr] = vw.x; Ws[lc + 1][lr] = vw.y; Ws[lc + 2][lr] = vw.z; Ws[lc + 3][lr] = vw.w;
        __syncthreads();
        #pragma unroll
        for (int kk = 0; kk < 16; ++kk) {
            float4 av = *reinterpret_cast<const float4*>(&As[kk][ty * 4]);
            float4 bv = *reinterpret_cast<const float4*>(&Ws[kk][tx * 4]);
            float a[4] = {av.x, av.y, av.z, av.w};
            float b[4] = {bv.x, bv.y, bv.z, bv.w};
            #pragma unroll
            for (int i = 0; i < 4; ++i)
                #pragma unroll
                for (int j = 0; j < 4; ++j) acc[i][j] += a[i] * b[j];
        }
        __syncthreads();
    }
    #pragma unroll
    for (int i = 0; i < 4; ++i) {
        int m = m0 + ty * 4 + i;
        if (m >= M) continue;
        float4 v;
        float* vv = (float*)&v;
        #pragma unroll
        for (int j = 0; j < 4; ++j) {
            float r = acc[i][j] + bias[n0 + tx * 4 + j];
            if (act == 1) r = fmaxf(r, 0.f);
            vv[j] = r;
        }
        *reinterpret_cast<float4*>(&C[(size_t)m * N + n0 + tx * 4]) = v;
    }
}

// ---------------- residual add + LayerNorm (row-wise over E=768) ----------------
__global__ __launch_bounds__(256) void add_ln_kernel(
    const float* __restrict__ h, const float* __restrict__ res,
    const float* __restrict__ s, const float* __restrict__ bb,
    float* __restrict__ out, int has_res)
{
    int row = blockIdx.x;
    int tid = threadIdx.x;
    __shared__ float sm[8];
    float v[3];
    #pragma unroll
    for (int j = 0; j < 3; ++j) {
        int e = tid + j * 256;
        float x = h[(size_t)row * E_ + e];
        if (has_res) x += res[(size_t)row * E_ + e];
        v[j] = x;
    }
    float sum = v[0] + v[1] + v[2];
    #pragma unroll
    for (int o = 32; o >= 1; o >>= 1) sum += __shfl_xor(sum, o);
    int wid = tid >> 6, lane = tid & 63;
    if (lane == 0) sm[wid] = sum;
    __syncthreads();
    if (tid == 0) sm[0] = sm[0] + sm[1] + sm[2] + sm[3];
    __syncthreads();
    float mu = sm[0] * (1.0f / E_);
    __syncthreads();
    float sq = 0.f;
    #pragma unroll
    for (int j = 0; j < 3; ++j) { float d = v[j] - mu; sq += d * d; }
    #pragma unroll
    for (int o = 32; o >= 1; o >>= 1) sq += __shfl_xor(sq, o);
    if (lane == 0) sm[wid] = sq;
    __syncthreads();
    if (tid == 0) sm[0] = sm[0] + sm[1] + sm[2] + sm[3];
    __syncthreads();
    float rstd = rsqrtf(sm[0] * (1.0f / E_) + 1e-5f);
    #pragma unroll
    for (int j = 0; j < 3; ++j) {
        int e = tid + j * 256;
        out[(size_t)row * E_ + e] = (v[j] - mu) * rstd * s[e] + bb[e];
    }
}

// ---------------- attention: one block per (b, head), tokens [start, 62) ----------------
__global__ __launch_bounds__(256) void attn_kernel(
    const float* __restrict__ qkv, float* __restrict__ obuf, int start)
{
    int h = blockIdx.x, b = blockIdx.y;
    int S = TOK - start;
    int tid = threadIdx.x;
    int row = tid >> 6, lane = tid & 63;
    __shared__ float klds[64][65];
    __shared__ float vlds[64][65];
    __shared__ float qlds[4][64];
    __shared__ float plds[4][64];
    const size_t basebh = (size_t)b * TOK * 2304 + h * 64;

    for (int idx = tid; idx < S * 64; idx += 256) {
        int j = idx >> 6, d = idx & 63;
        klds[j][d] = qkv[basebh + (size_t)(start + j) * 2304 + 768 + d];
        vlds[j][d] = qkv[basebh + (size_t)(start + j) * 2304 + 1536 + d];
    }
    __syncthreads();

    for (int qi0 = start; qi0 < TOK; qi0 += 4) {
        int qi = qi0 + row;
        qlds[row][lane] = (qi < TOK) ? qkv[basebh + (size_t)qi * 2304 + lane] : 0.f;
        __syncthreads();
        float sv = -1e30f;
        if (lane < S && qi < TOK) {
            float acc = 0.f;
            #pragma unroll
            for (int d = 0; d < 64; ++d) acc += qlds[row][d] * klds[lane][d];
            sv = acc * 0.125f;
        }
        float m = sv;
        #pragma unroll
        for (int o = 32; o >= 1; o >>= 1) m = fmaxf(m, __shfl_xor(m, o));
        float p = expf(sv - m);                 // inactive lanes: exp(-1e30) -> 0
        float l = p;
        #pragma unroll
        for (int o = 32; o >= 1; o >>= 1) l += __shfl_xor(l, o);
        p /= l;
        plds[row][lane] = p;
        __syncthreads();
        float o_acc = 0.f;
        for (int j = 0; j < S; ++j) o_acc += plds[row][j] * vlds[j][lane];
        if (qi < TOK) obuf[(size_t)(b * TOK + qi) * E_ + h * 64 + lane] = o_acc;
        __syncthreads();
    }
}

// ---------------- small glue kernels ----------------
__global__ __launch_bounds__(256) void mean_kernel(const float* __restrict__ x, float* __restrict__ xmean)
{
    int bc = blockIdx.x;
    const float* p = x + (size_t)bc * IMG_ * IMG_;
    float s = 0.f;
    for (int i = threadIdx.x; i < IMG_ * IMG_; i += 256) s += p[i];
    #pragma unroll
    for (int o = 32; o >= 1; o >>= 1) s += __shfl_xor(s, o);
    __shared__ float sm[4];
    int wid = threadIdx.x >> 6, lane = threadIdx.x & 63;
    if (lane == 0) sm[wid] = s;
    __syncthreads();
    if (threadIdx.x == 0) xmean[bc] = (sm[0] + sm[1] + sm[2] + sm[3]) / (float)(IMG_ * IMG_);
}

__global__ void ximg_kernel(const float* __restrict__ xmean, const float* __restrict__ Wbb,
                            const float* __restrict__ bbb, float* __restrict__ ximg)
{
    int idx = blockIdx.x * 256 + threadIdx.x;
    if (idx >= B_ * E_) return;
    int e = idx % E_, b = idx / E_;
    ximg[idx] = xmean[b * 3 + 0] * Wbb[0 * E_ + e]
              + xmean[b * 3 + 1] * Wbb[1 * E_ + e]
              + xmean[b * 3 + 2] * Wbb[2 * E_ + e] + bbb[e];
}

__global__ void im2col_kernel(const float* __restrict__ x, float* __restrict__ Pm)
{
    int idx = blockIdx.x * 256 + threadIdx.x;
    if (idx >= B_ * NPATCH * 3072) return;
    int k = idx % 3072;
    int rowp = idx / 3072;
    int n = rowp % NPATCH, b = rowp / NPATCH;
    int i = n / G_, j = n % G_;
    int c = k >> 10;
    int r = k & 1023;
    int p = r >> 5, q = r & 31;
    Pm[idx] = x[(((size_t)b * C_ + c) * IMG_ + i * P_ + p) * IMG_ + j * P_ + q];
}

__global__ void build_h0_kernel(const float* __restrict__ pmout, const float* __restrict__ cls,
                                const float* __restrict__ pos, float* __restrict__ hbuf)
{
    int idx = blockIdx.x * 256 + threadIdx.x;
    if (idx >= MROWS * E_) return;
    int e = idx % E_;
    int t = (idx / E_) % TOK;
    int b = idx / (E_ * TOK);
    float v = 0.f;
    if (t >= 12) {
        int sseq = t - 12;
        float base = (sseq == 0) ? cls[e] : pmout[((size_t)b * NPATCH + (sseq - 1)) * E_ + e];
        v = base + pos[sseq * E_ + e];
    }
    hbuf[idx] = v;
}

__global__ void prepend_kernel(const float* __restrict__ ximg, float* __restrict__ hbuf, int t)
{
    int idx = blockIdx.x * 256 + threadIdx.x;
    if (idx >= B_ * E_) return;
    int e = idx % E_, b = idx / E_;
    hbuf[((size_t)b * TOK + t) * E_ + e] = ximg[idx];
}

// ---------------- head: out1 = gelu(hf @ Wh1^T + bh1), split-K ----------------
__global__ __launch_bounds__(256) void head1_partial_kernel(
    const float* __restrict__ hf, const float* __restrict__ Wh1, float* __restrict__ part)
{
    int n0 = blockIdx.x * 64;
    int kc = blockIdx.y;
    int tid = threadIdx.x;
    __shared__ float hl[32][65];
    __shared__ float wl[64][65];
    int nloc = tid & 63, bq = tid >> 6;
    float acc[8] = {};
    const int KCH = FLAT_ / 8;   // 5952
    int kbeg = kc * KCH, kend = kbeg + KCH;
    for (int k0 = kbeg; k0 < kend; k0 += 64) {
        for (int idx = tid; idx < 32 * 64; idx += 256) {
            int b = idx >> 6, kk = idx & 63;
            hl[b][kk] = hf[(size_t)b * FLAT_ + k0 + kk];
        }
        for (int idx = tid; idx < 64 * 64; idx += 256) {
            int nn = idx >> 6, kk = idx & 63;
            wl[nn][kk] = Wh1[(size_t)(n0 + nn) * FLAT_ + k0 + kk];
        }
        __syncthreads();
        #pragma unroll 8
        for (int kk = 0; kk < 64; ++kk) {
            float w = wl[nloc][kk];
            #pragma unroll
            for (int j = 0; j < 8; ++j) acc[j] += w * hl[bq + 4 * j][kk];
        }
        __syncthreads();
    }
    #pragma unroll
    for (int j = 0; j < 8; ++j) {
        int b = bq + 4 * j;
        part[((size_t)kc * B_ + b) * MLP_ + n0 + nloc] = acc[j];
    }
}

__global__ void head1_fin_kernel(const float* __restrict__ part, const float* __restrict__ bh1,
                                 float* __restrict__ out1)
{
    int idx = blockIdx.x * 256 + threadIdx.x;
    if (idx >= B_ * MLP_) return;
    int n = idx % MLP_, b = idx / MLP_;
    float s = bh1[n];
    #pragma unroll
    for (int kc = 0; kc < 8; ++kc) s += part[((size_t)kc * B_ + b) * MLP_ + n];
    out1[idx] = 0.5f * s * (1.0f + erff(s * 0.70710678118654752f));
}

__global__ __launch_bounds__(256) void head2_kernel(const float* __restrict__ out1,
                                                    const float* __restrict__ Wh2,
                                                    const float* __restrict__ bh2,
                                                    float* __restrict__ out)
{
    int bc = blockIdx.x;     // b*NC + c
    int b = bc / NC_, c = bc % NC_;
    float s = 0.f;
    for (int n = threadIdx.x; n < MLP_; n += 256) s += out1[(size_t)b * MLP_ + n] * Wh2[(size_t)c * MLP_ + n];
    #pragma unroll
    for (int o = 32; o >= 1; o >>= 1) s += __shfl_xor(s, o);
    __shared__ float sm[4];
    int wid = threadIdx.x >> 6, lane = threadIdx.x & 63;
    if (lane == 0) sm[wid] = s;
    __syncthreads();
    if (threadIdx.x == 0) out[bc] = sm[0] + sm[1] + sm[2] + sm[3] + bh2[c];
}

// ---------------- driver ----------------
extern "C" void kernel_launch(void* const* d_in, const int* in_sizes, int n_in,
                              void* d_out, int out_size, void* d_ws, size_t ws_size,
                              hipStream_t stream)
{
    (void)in_sizes; (void)n_in; (void)out_size; (void)ws_size;
    const float* x    = (const float*)d_in[0];
    const float* Wp   = (const float*)d_in[1];
    const float* bp   = (const float*)d_in[2];
    const float* cls  = (const float*)d_in[3];
    const float* pos  = (const float*)d_in[4];
    const float* Wbb  = (const float*)d_in[5];
    const float* bbb  = (const float*)d_in[6];
    const float* Wqkv = (const float*)d_in[7];
    const float* bqkv = (const float*)d_in[8];
    const float* Wo   = (const float*)d_in[9];
    const float* bo   = (const float*)d_in[10];
    const float* ln1s = (const float*)d_in[11];
    const float* ln1b = (const float*)d_in[12];
    const float* W1   = (const float*)d_in[13];
    const float* b1   = (const float*)d_in[14];
    const float* W2   = (const float*)d_in[15];
    const float* b2   = (const float*)d_in[16];
    const float* ln2s = (const float*)d_in[17];
    const float* ln2b = (const float*)d_in[18];
    const float* lnfs = (const float*)d_in[19];
    const float* lnfb = (const float*)d_in[20];
    const float* Wh1  = (const float*)d_in[21];
    const float* bh1  = (const float*)d_in[22];
    const float* Wh2  = (const float*)d_in[23];
    const float* bh2  = (const float*)d_in[24];
    float* out = (float*)d_out;

    float* ws = (float*)d_ws;
    size_t off = 0;
    float* hbuf = ws + off; off += (size_t)MROWS * E_;          // 1,523,712
    float* big1 = ws + off; off += 4816896;                     // qkv buf / im2col Pm
    float* big2 = ws + off; off += (size_t)MROWS * DFF_;        // ff buf / final hf
    float* obuf = ws + off; off += (size_t)MROWS * E_;          // attn out / pmout
    float* tmp  = ws + off; off += (size_t)MROWS * E_;
    float* ximg = ws + off; off += B_ * E_;
    float* xmean= ws + off; off += 128;
    float* part = ws + off; off += 8 * B_ * MLP_;
    float* out1 = ws + off; off += B_ * MLP_;

    float* qkvbuf = big1;
    float* Pm     = big1;
    float* ffbuf  = big2;
    float* hf     = big2;
    float* pmout  = obuf;

    // backbone token
    mean_kernel<<<B_ * C_, 256, 0, stream>>>(x, xmean);
    ximg_kernel<<<(B_ * E_ + 255) / 256, 256, 0, stream>>>(xmean, Wbb, bbb, ximg);
    // patch embedding
    im2col_kernel<<<(B_ * NPATCH * 3072 + 255) / 256, 256, 0, stream>>>(x, Pm);
    gemm_bias_kernel<<<dim3(E_ / 64, (B_ * NPATCH + 63) / 64), 256, 0, stream>>>(
        Pm, Wp, bp, pmout, B_ * NPATCH, E_, 3072, 0);
    build_h0_kernel<<<(MROWS * E_ + 255) / 256, 256, 0, stream>>>(pmout, cls, pos, hbuf);

    for (int i = 0; i < L_; ++i) {
        int start = 12 - i;
        gemm_bias_kernel<<<dim3(2304 / 64, MROWS / 64), 256, 0, stream>>>(
            hbuf, Wqkv + (size_t)i * 2304 * E_, bqkv + i * 2304, qkvbuf, MROWS, 2304, E_, 0);
        attn_kernel<<<dim3(NH_, B_), 256, 0, stream>>>(qkvbuf, obuf, start);
        gemm_bias_kernel<<<dim3(E_ / 64, MROWS / 64), 256, 0, stream>>>(
            obuf, Wo + (size_t)i * E_ * E_, bo + i * E_, tmp, MROWS, E_, E_, 0);
        add_ln_kernel<<<MROWS, 256, 0, stream>>>(hbuf, tmp, ln1s + i * E_, ln1b + i * E_, hbuf, 1);
        gemm_bias_kernel<<<dim3(DFF_ / 64, MROWS / 64), 256, 0, stream>>>(
            hbuf, W1 + (size_t)i * DFF_ * E_, b1 + i * DFF_, ffbuf, MROWS, DFF_, E_, 1);
        gemm_bias_kernel<<<dim3(E_ / 64, MROWS / 64), 256, 0, stream>>>(
            ffbuf, W2 + (size_t)i * E_ * DFF_, b2 + i * E_, tmp, MROWS, E_, DFF_, 0);
        add_ln_kernel<<<MROWS, 256, 0, stream>>>(hbuf, tmp, ln2s + i * E_, ln2b + i * E_, hbuf, 1);
        prepend_kernel<<<(B_ * E_ + 255) / 256, 256, 0, stream>>>(ximg, hbuf, 11 - i);
    }

    // final LN + head
    add_ln_kernel<<<MROWS, 256, 0, stream>>>(hbuf, nullptr, lnfs, lnfb, hf, 0);
    head1_partial_kernel<<<dim3(MLP_ / 64, 8), 256, 0, stream>>>(hf, Wh1, part);
    head1_fin_kernel<<<(B_ * MLP_ + 255) / 256, 256, 0, stream>>>(part, bh1, out1);
    head2_kernel<<<B_ * NC_, 256, 0, stream>>>(out1, Wh2, bh2, out);
}

// Round 2
// 2794.073 us; speedup vs baseline: 2.7422x; 2.7422x over previous
//
#include <hip/hip_runtime.h>
#include <math.h>

#define B_ 32
#define C_ 3
#define IMG_ 224
#define P_ 32
#define G_ 7
#define NPATCH 49
#define E_ 768
#define NH_ 12
#define L_ 12
#define DFF_ 3072
#define MLP_ 2048
#define NC_ 5
#define TOK 62
#define MROWS (B_*TOK)      // 1984
#define FLAT_ (TOK*E_)      // 47616
#define MPAD 2048
#define PMROWS (B_*NPATCH)  // 1568
#define PMPAD 1664          // 13*128

typedef __bf16 bf16x8 __attribute__((ext_vector_type(8)));
typedef float f32x4 __attribute__((ext_vector_type(4)));

__device__ inline unsigned short f2bf(float f) {
    unsigned u = __float_as_uint(f);
    u += 0x7FFF + ((u >> 16) & 1);
    return (unsigned short)(u >> 16);
}

// ---------------- fp32 -> bf16 conversion (vectorized) ----------------
__global__ __launch_bounds__(256) void cvt_bf16_kernel(
    const float* __restrict__ in, unsigned short* __restrict__ out, int n4)
{
    int i = blockIdx.x * 256 + threadIdx.x;
    if (i >= n4) return;
    float4 v = reinterpret_cast<const float4*>(in)[i];
    ushort4 o;
    o.x = f2bf(v.x); o.y = f2bf(v.y); o.z = f2bf(v.z); o.w = f2bf(v.w);
    reinterpret_cast<ushort4*>(out)[i] = o;
}

// ---------------- bf16 MFMA GEMM: C[m,n] = act(sum_k A[m,k]*W[n,k] + bias[n]) ----------------
// A: (Mpad x K) bf16 row-major. W: (N x K) bf16 row-major. BM=128, BN=64, BK=64.
#define BKG 64
#define PADK 72
__global__ __launch_bounds__(256) void gemm_mfma(
    const unsigned short* __restrict__ A, const unsigned short* __restrict__ W,
    const float* __restrict__ bias, void* __restrict__ Cout,
    int M, int N, int K, int act, int outbf)
{
    __shared__ unsigned short As[128][PADK];
    __shared__ unsigned short Ws[64][PADK];
    int tid = threadIdx.x;
    int m0 = blockIdx.y * 128, n0 = blockIdx.x * 64;
    int wid = tid >> 6, lane = tid & 63;
    int wm = wid >> 1, wn = wid & 1;
    int lr = lane & 15, lg = lane >> 4;

    f32x4 acc[4][2];
    #pragma unroll
    for (int mi = 0; mi < 4; ++mi)
        #pragma unroll
        for (int ni = 0; ni < 2; ++ni)
            acc[mi][ni] = (f32x4){0.f, 0.f, 0.f, 0.f};

    for (int k0 = 0; k0 < K; k0 += BKG) {
        #pragma unroll
        for (int t = 0; t < 4; ++t) {
            int i = tid + t * 256;          // 0..1023
            int r = i >> 3, kk = (i & 7) * 8;
            uint4 v = *reinterpret_cast<const uint4*>(&A[(size_t)(m0 + r) * K + k0 + kk]);
            *reinterpret_cast<uint4*>(&As[r][kk]) = v;
        }
        #pragma unroll
        for (int t = 0; t < 2; ++t) {
            int i = tid + t * 256;          // 0..511
            int r = i >> 3, kk = (i & 7) * 8;
            uint4 v = *reinterpret_cast<const uint4*>(&W[(size_t)(n0 + r) * K + k0 + kk]);
            *reinterpret_cast<uint4*>(&Ws[r][kk]) = v;
        }
        __syncthreads();
        #pragma unroll
        for (int ks = 0; ks < BKG; ks += 32) {
            bf16x8 af[4], bfr[2];
            #pragma unroll
            for (int mi = 0; mi < 4; ++mi)
                af[mi] = *reinterpret_cast<const bf16x8*>(&As[wm * 64 + mi * 16 + lr][ks + lg * 8]);
            #pragma unroll
            for (int ni = 0; ni < 2; ++ni)
                bfr[ni] = *reinterpret_cast<const bf16x8*>(&Ws[wn * 32 + ni * 16 + lr][ks + lg * 8]);
            #pragma unroll
            for (int mi = 0; mi < 4; ++mi)
                #pragma unroll
                for (int ni = 0; ni < 2; ++ni)
                    acc[mi][ni] = __builtin_amdgcn_mfma_f32_16x16x32_bf16(af[mi], bfr[ni], acc[mi][ni], 0, 0, 0);
        }
        __syncthreads();
    }

    float* Cf = (float*)Cout;
    unsigned short* Cb = (unsigned short*)Cout;
    #pragma unroll
    for (int mi = 0; mi < 4; ++mi) {
        #pragma unroll
        for (int rr = 0; rr < 4; ++rr) {
            int row = m0 + wm * 64 + mi * 16 + lg * 4 + rr;
            if (row >= M) continue;
            #pragma unroll
            for (int ni = 0; ni < 2; ++ni) {
                int col = n0 + wn * 32 + ni * 16 + lr;
                float v = acc[mi][ni][rr] + bias[col];
                if (act) v = fmaxf(v, 0.f);
                if (outbf) Cb[(size_t)row * N + col] = f2bf(v);
                else       Cf[(size_t)row * N + col] = v;
            }
        }
    }
}

// ---------------- residual add + LayerNorm (row over E=768), writes f32 + optional bf16 ----------------
__global__ __launch_bounds__(256) void add_ln_kernel(
    const float* __restrict__ h, const float* __restrict__ res,
    const float* __restrict__ s, const float* __restrict__ bb,
    float* __restrict__ out, unsigned short* __restrict__ outbf, int has_res)
{
    int row = blockIdx.x;
    int tid = threadIdx.x;
    __shared__ float sm[8];
    float v[3];
    #pragma unroll
    for (int j = 0; j < 3; ++j) {
        int e = tid + j * 256;
        float x = h[(size_t)row * E_ + e];
        if (has_res) x += res[(size_t)row * E_ + e];
        v[j] = x;
    }
    float sum = v[0] + v[1] + v[2];
    #pragma unroll
    for (int o = 32; o >= 1; o >>= 1) sum += __shfl_xor(sum, o);
    int wid = tid >> 6, lane = tid & 63;
    if (lane == 0) sm[wid] = sum;
    __syncthreads();
    if (tid == 0) sm[0] = sm[0] + sm[1] + sm[2] + sm[3];
    __syncthreads();
    float mu = sm[0] * (1.0f / E_);
    __syncthreads();
    float sq = 0.f;
    #pragma unroll
    for (int j = 0; j < 3; ++j) { float d = v[j] - mu; sq += d * d; }
    #pragma unroll
    for (int o = 32; o >= 1; o >>= 1) sq += __shfl_xor(sq, o);
    if (lane == 0) sm[wid] = sq;
    __syncthreads();
    if (tid == 0) sm[0] = sm[0] + sm[1] + sm[2] + sm[3];
    __syncthreads();
    float rstd = rsqrtf(sm[0] * (1.0f / E_) + 1e-5f);
    #pragma unroll
    for (int j = 0; j < 3; ++j) {
        int e = tid + j * 256;
        float r = (v[j] - mu) * rstd * s[e] + bb[e];
        out[(size_t)row * E_ + e] = r;
        if (outbf) outbf[(size_t)row * E_ + e] = f2bf(r);
    }
}

// ---------------- attention: one block per (b, head), tokens [start, 62), bf16 out ----------------
__global__ __launch_bounds__(256) void attn_kernel(
    const float* __restrict__ qkv, unsigned short* __restrict__ obf, int start)
{
    int h = blockIdx.x, b = blockIdx.y;
    int S = TOK - start;
    int tid = threadIdx.x;
    int row = tid >> 6, lane = tid & 63;
    __shared__ float klds[64][65];
    __shared__ float vlds[64][65];
    __shared__ float qlds[4][64];
    __shared__ float plds[4][64];
    const size_t basebh = (size_t)b * TOK * 2304 + h * 64;

    for (int idx = tid; idx < S * 64; idx += 256) {
        int j = idx >> 6, d = idx & 63;
        klds[j][d] = qkv[basebh + (size_t)(start + j) * 2304 + 768 + d];
        vlds[j][d] = qkv[basebh + (size_t)(start + j) * 2304 + 1536 + d];
    }
    __syncthreads();

    for (int qi0 = start; qi0 < TOK; qi0 += 4) {
        int qi = qi0 + row;
        qlds[row][lane] = (qi < TOK) ? qkv[basebh + (size_t)qi * 2304 + lane] : 0.f;
        __syncthreads();
        float sv = -1e30f;
        if (lane < S && qi < TOK) {
            float acc = 0.f;
            #pragma unroll
            for (int d = 0; d < 64; ++d) acc += qlds[row][d] * klds[lane][d];
            sv = acc * 0.125f;
        }
        float m = sv;
        #pragma unroll
        for (int o = 32; o >= 1; o >>= 1) m = fmaxf(m, __shfl_xor(m, o));
        float p = expf(sv - m);
        float l = p;
        #pragma unroll
        for (int o = 32; o >= 1; o >>= 1) l += __shfl_xor(l, o);
        p /= l;
        plds[row][lane] = p;
        __syncthreads();
        float o_acc = 0.f;
        for (int j = 0; j < S; ++j) o_acc += plds[row][j] * vlds[j][lane];
        if (qi < TOK) obf[(size_t)(b * TOK + qi) * E_ + h * 64 + lane] = f2bf(o_acc);
        __syncthreads();
    }
}

// ---------------- small glue kernels ----------------
__global__ __launch_bounds__(256) void mean_kernel(const float* __restrict__ x, float* __restrict__ xmean)
{
    int bc = blockIdx.x;
    const float* p = x + (size_t)bc * IMG_ * IMG_;
    float s = 0.f;
    for (int i = threadIdx.x; i < IMG_ * IMG_; i += 256) s += p[i];
    #pragma unroll
    for (int o = 32; o >= 1; o >>= 1) s += __shfl_xor(s, o);
    __shared__ float sm[4];
    int wid = threadIdx.x >> 6, lane = threadIdx.x & 63;
    if (lane == 0) sm[wid] = s;
    __syncthreads();
    if (threadIdx.x == 0) xmean[bc] = (sm[0] + sm[1] + sm[2] + sm[3]) / (float)(IMG_ * IMG_);
}

__global__ void ximg_kernel(const float* __restrict__ xmean, const float* __restrict__ Wbb,
                            const float* __restrict__ bbb, float* __restrict__ ximg)
{
    int idx = blockIdx.x * 256 + threadIdx.x;
    if (idx >= B_ * E_) return;
    int e = idx % E_, b = idx / E_;
    ximg[idx] = xmean[b * 3 + 0] * Wbb[0 * E_ + e]
              + xmean[b * 3 + 1] * Wbb[1 * E_ + e]
              + xmean[b * 3 + 2] * Wbb[2 * E_ + e] + bbb[e];
}

__global__ void im2col_kernel(const float* __restrict__ x, unsigned short* __restrict__ Pm)
{
    int idx = blockIdx.x * 256 + threadIdx.x;
    if (idx >= PMROWS * 3072) return;
    int k = idx % 3072;
    int rowp = idx / 3072;
    int n = rowp % NPATCH, b = rowp / NPATCH;
    int i = n / G_, j = n % G_;
    int c = k >> 10;
    int r = k & 1023;
    int p = r >> 5, q = r & 31;
    Pm[idx] = f2bf(x[(((size_t)b * C_ + c) * IMG_ + i * P_ + p) * IMG_ + j * P_ + q]);
}

__global__ void build_h0_kernel(const float* __restrict__ pmout, const float* __restrict__ cls,
                                const float* __restrict__ pos, float* __restrict__ hbuf,
                                unsigned short* __restrict__ hbf)
{
    int idx = blockIdx.x * 256 + threadIdx.x;
    if (idx >= MROWS * E_) return;
    int e = idx % E_;
    int t = (idx / E_) % TOK;
    int b = idx / (E_ * TOK);
    float v = 0.f;
    if (t >= 12) {
        int sseq = t - 12;
        float base = (sseq == 0) ? cls[e] : pmout[((size_t)b * NPATCH + (sseq - 1)) * E_ + e];
        v = base + pos[sseq * E_ + e];
    }
    hbuf[idx] = v;
    hbf[idx] = f2bf(v);
}

__global__ void prepend_kernel(const float* __restrict__ ximg, float* __restrict__ hbuf,
                               unsigned short* __restrict__ hbf, int t)
{
    int idx = blockIdx.x * 256 + threadIdx.x;
    if (idx >= B_ * E_) return;
    int e = idx % E_, b = idx / E_;
    float v = ximg[idx];
    hbuf[((size_t)b * TOK + t) * E_ + e] = v;
    hbf[((size_t)b * TOK + t) * E_ + e] = f2bf(v);
}

// ---------------- head1: split-K 62 chunks of 768; block = 256 n, all 32 b ----------------
__global__ __launch_bounds__(256) void head1_partial2(
    const float* __restrict__ hf, const float* __restrict__ Wh1, float* __restrict__ part)
{
    __shared__ float hl[32][128];     // 16 KB: hf chunk for all 32 batches
    __shared__ float wl[256][36];     // 36.8 KB: W strip, 256 n x 32 k (+pad)
    int tid = threadIdx.x;
    int n = blockIdx.x * 256 + tid;
    int kc = blockIdx.y;
    const size_t base = (size_t)kc * 768;

    float acc[32];
    #pragma unroll
    for (int b = 0; b < 32; ++b) acc[b] = 0.f;

    for (int k0 = 0; k0 < 768; k0 += 128) {
        #pragma unroll
        for (int t = 0; t < 4; ++t) {
            int i = tid + t * 256;           // 0..1023
            int b = i >> 5, kk = (i & 31) * 4;
            *reinterpret_cast<float4*>(&hl[b][kk]) =
                *reinterpret_cast<const float4*>(&hf[(size_t)b * FLAT_ + base + k0 + kk]);
        }
        __syncthreads();
        for (int strip = 0; strip < 4; ++strip) {
            #pragma unroll
            for (int t = 0; t < 8; ++t) {
                int i = tid + t * 256;       // 0..2047
                int r = i >> 3, kk = (i & 7) * 4;
                *reinterpret_cast<float4*>(&wl[r][kk]) =
                    *reinterpret_cast<const float4*>(&Wh1[(size_t)(blockIdx.x * 256 + r) * FLAT_ + base + k0 + strip * 32 + kk]);
            }
            __syncthreads();
            #pragma unroll
            for (int k4 = 0; k4 < 8; ++k4) {
                float4 w = *reinterpret_cast<const float4*>(&wl[tid][k4 * 4]);
                #pragma unroll
                for (int b = 0; b < 32; ++b) {
                    float4 h4 = *reinterpret_cast<const float4*>(&hl[b][strip * 32 + k4 * 4]);
                    acc[b] += w.x * h4.x + w.y * h4.y + w.z * h4.z + w.w * h4.w;
                }
            }
            __syncthreads();
        }
    }
    #pragma unroll
    for (int b = 0; b < 32; ++b)
        part[((size_t)kc * 32 + b) * MLP_ + n] = acc[b];
}

__global__ void head1_fin_kernel(const float* __restrict__ part, const float* __restrict__ bh1,
                                 float* __restrict__ out1)
{
    int idx = blockIdx.x * 256 + threadIdx.x;
    if (idx >= B_ * MLP_) return;
    int n = idx % MLP_, b = idx / MLP_;
    float s = bh1[n];
    for (int kc = 0; kc < 62; ++kc) s += part[((size_t)kc * 32 + b) * MLP_ + n];
    out1[idx] = 0.5f * s * (1.0f + erff(s * 0.70710678118654752f));
}

__global__ __launch_bounds__(256) void head2_kernel(const float* __restrict__ out1,
                                                    const float* __restrict__ Wh2,
                                                    const float* __restrict__ bh2,
                                                    float* __restrict__ out)
{
    int bc = blockIdx.x;
    int b = bc / NC_, c = bc % NC_;
    float s = 0.f;
    for (int nn = threadIdx.x; nn < MLP_; nn += 256) s += out1[(size_t)b * MLP_ + nn] * Wh2[(size_t)c * MLP_ + nn];
    #pragma unroll
    for (int o = 32; o >= 1; o >>= 1) s += __shfl_xor(s, o);
    __shared__ float sm[4];
    int wid = threadIdx.x >> 6, lane = threadIdx.x & 63;
    if (lane == 0) sm[wid] = s;
    __syncthreads();
    if (threadIdx.x == 0) out[bc] = sm[0] + sm[1] + sm[2] + sm[3] + bh2[c];
}

// ---------------- driver ----------------
extern "C" void kernel_launch(void* const* d_in, const int* in_sizes, int n_in,
                              void* d_out, int out_size, void* d_ws, size_t ws_size,
                              hipStream_t stream)
{
    (void)in_sizes; (void)n_in; (void)out_size; (void)ws_size;
    const float* x    = (const float*)d_in[0];
    const float* Wp   = (const float*)d_in[1];
    const float* bp   = (const float*)d_in[2];
    const float* cls  = (const float*)d_in[3];
    const float* pos  = (const float*)d_in[4];
    const float* Wbb  = (const float*)d_in[5];
    const float* bbb  = (const float*)d_in[6];
    const float* Wqkv = (const float*)d_in[7];
    const float* bqkv = (const float*)d_in[8];
    const float* Wo   = (const float*)d_in[9];
    const float* bo   = (const float*)d_in[10];
    const float* ln1s = (const float*)d_in[11];
    const float* ln1b = (const float*)d_in[12];
    const float* W1   = (const float*)d_in[13];
    const float* b1   = (const float*)d_in[14];
    const float* W2   = (const float*)d_in[15];
    const float* b2   = (const float*)d_in[16];
    const float* ln2s = (const float*)d_in[17];
    const float* ln2b = (const float*)d_in[18];
    const float* lnfs = (const float*)d_in[19];
    const float* lnfb = (const float*)d_in[20];
    const float* Wh1  = (const float*)d_in[21];
    const float* bh1  = (const float*)d_in[22];
    const float* Wh2  = (const float*)d_in[23];
    const float* bh2  = (const float*)d_in[24];
    float* out = (float*)d_out;

    float* ws = (float*)d_ws;
    size_t off = 0;
    float* hbuf = ws + off; off += (size_t)MROWS * E_;              // residual stream f32
    float* tmp  = ws + off; off += (size_t)MROWS * E_;              // gemm f32 out / pmout
    float* hf   = ws + off; off += (size_t)MROWS * E_;              // final LN out
    float* qkvbuf = ws + off; off += (size_t)MROWS * 2304;          // qkv f32 / part (aliased)
    unsigned short* hbf  = (unsigned short*)(ws + off); off += (size_t)MPAD * E_ / 2;
    unsigned short* obf  = (unsigned short*)(ws + off); off += (size_t)MPAD * E_ / 2;
    unsigned short* ffbf = (unsigned short*)(ws + off); off += (size_t)MPAD * DFF_ / 2;  // also Pmbf
    unsigned short* wbf  = (unsigned short*)(ws + off); off += (size_t)DFF_ * E_ / 2;
    float* ximg = ws + off; off += B_ * E_;
    float* xmean= ws + off; off += 128;
    float* out1 = ws + off; off += B_ * MLP_;

    float* pmout = tmp;
    float* part  = qkvbuf;
    unsigned short* Pmbf = ffbf;

    // backbone token
    mean_kernel<<<B_ * C_, 256, 0, stream>>>(x, xmean);
    ximg_kernel<<<(B_ * E_ + 255) / 256, 256, 0, stream>>>(xmean, Wbb, bbb, ximg);

    // patch embedding (bf16 MFMA)
    im2col_kernel<<<(PMROWS * 3072 + 255) / 256, 256, 0, stream>>>(x, Pmbf);
    cvt_bf16_kernel<<<(E_ * 3072 / 4 + 255) / 256, 256, 0, stream>>>(Wp, wbf, E_ * 3072 / 4);
    gemm_mfma<<<dim3(E_ / 64, PMPAD / 128), 256, 0, stream>>>(Pmbf, wbf, bp, pmout, PMROWS, E_, 3072, 0, 0);
    build_h0_kernel<<<(MROWS * E_ + 255) / 256, 256, 0, stream>>>(pmout, cls, pos, hbuf, hbf);

    for (int i = 0; i < L_; ++i) {
        int start = 12 - i;
        cvt_bf16_kernel<<<(2304 * E_ / 4 + 255) / 256, 256, 0, stream>>>(
            Wqkv + (size_t)i * 2304 * E_, wbf, 2304 * E_ / 4);
        gemm_mfma<<<dim3(2304 / 64, MPAD / 128), 256, 0, stream>>>(
            hbf, wbf, bqkv + i * 2304, qkvbuf, MROWS, 2304, E_, 0, 0);
        attn_kernel<<<dim3(NH_, B_), 256, 0, stream>>>(qkvbuf, obf, start);
        cvt_bf16_kernel<<<(E_ * E_ / 4 + 255) / 256, 256, 0, stream>>>(
            Wo + (size_t)i * E_ * E_, wbf, E_ * E_ / 4);
        gemm_mfma<<<dim3(E_ / 64, MPAD / 128), 256, 0, stream>>>(
            obf, wbf, bo + i * E_, tmp, MROWS, E_, E_, 0, 0);
        add_ln_kernel<<<MROWS, 256, 0, stream>>>(hbuf, tmp, ln1s + i * E_, ln1b + i * E_, hbuf, hbf, 1);
        cvt_bf16_kernel<<<(DFF_ * E_ / 4 + 255) / 256, 256, 0, stream>>>(
            W1 + (size_t)i * DFF_ * E_, wbf, DFF_ * E_ / 4);
        gemm_mfma<<<dim3(DFF_ / 64, MPAD / 128), 256, 0, stream>>>(
            hbf, wbf, b1 + i * DFF_, ffbf, MROWS, DFF_, E_, 1, 1);
        cvt_bf16_kernel<<<(E_ * DFF_ / 4 + 255) / 256, 256, 0, stream>>>(
            W2 + (size_t)i * E_ * DFF_, wbf, E_ * DFF_ / 4);
        gemm_mfma<<<dim3(E_ / 64, MPAD / 128), 256, 0, stream>>>(
            ffbf, wbf, b2 + i * E_, tmp, MROWS, E_, DFF_, 0, 0);
        add_ln_kernel<<<MROWS, 256, 0, stream>>>(hbuf, tmp, ln2s + i * E_, ln2b + i * E_, hbuf, hbf, 1);
        prepend_kernel<<<(B_ * E_ + 255) / 256, 256, 0, stream>>>(ximg, hbuf, hbf, 11 - i);
    }

    // final LN + head
    add_ln_kernel<<<MROWS, 256, 0, stream>>>(hbuf, nullptr, lnfs, lnfb, hf, nullptr, 0);
    head1_partial2<<<dim3(MLP_ / 256, 62), 256, 0, stream>>>(hf, Wh1, part);
    head1_fin_kernel<<<(B_ * MLP_ + 255) / 256, 256, 0, stream>>>(part, bh1, out1);
    head2_kernel<<<B_ * NC_, 256, 0, stream>>>(out1, Wh2, bh2, out);
}

// Round 3
// 2355.734 us; speedup vs baseline: 3.2524x; 1.1861x over previous
//
#include <hip/hip_runtime.h>
#include <math.h>

#define B_ 32
#define C_ 3
#define IMG_ 224
#define P_ 32
#define G_ 7
#define NPATCH 49
#define E_ 768
#define NH_ 12
#define L_ 12
#define DFF_ 3072
#define MLP_ 2048
#define NC_ 5
#define TOK 62
#define MROWS (B_*TOK)      // 1984
#define FLAT_ (TOK*E_)      // 47616
#define MPAD 2048
#define PMROWS (B_*NPATCH)  // 1568
#define PMPAD 1664          // 13*128
#define HKS 31              // head split-K
#define HKC (FLAT_/HKS)     // 1536

// layer weight segment sizes (elements) inside wbf
#define WQKV_SZ (2304*768)  // 1769472
#define WO_SZ   (768*768)   // 589824
#define W1_SZ   (3072*768)  // 2359296
#define W2_SZ   (768*3072)  // 2359296
#define WTOT    (WQKV_SZ+WO_SZ+W1_SZ+W2_SZ)

typedef __bf16 bf16x8 __attribute__((ext_vector_type(8)));
typedef float f32x4 __attribute__((ext_vector_type(4)));

__device__ inline unsigned short f2bf(float f) {
    unsigned u = __float_as_uint(f);
    u += 0x7FFF + ((u >> 16) & 1);
    return (unsigned short)(u >> 16);
}

__device__ inline unsigned cvtpk(float lo, float hi) {
    unsigned r;
    asm("v_cvt_pk_bf16_f32 %0, %1, %2" : "=v"(r) : "v"(lo), "v"(hi));
    return r;
}

#define GLDS(gsrc, ldst) __builtin_amdgcn_global_load_lds( \
    (__attribute__((address_space(1))) const void*)(gsrc), \
    (__attribute__((address_space(3))) void*)(ldst), 16, 0, 0)

// ---------------- fused 4-segment fp32 -> bf16 conversion ----------------
__global__ __launch_bounds__(256) void cvt4_kernel(
    const float* __restrict__ s0, int n0, const float* __restrict__ s1, int n1,
    const float* __restrict__ s2, int n2, const float* __restrict__ s3, int n3,
    unsigned short* __restrict__ out)
{
    int i = (blockIdx.x * 256 + threadIdx.x) * 4;
    int ntot = n0 + n1 + n2 + n3;
    if (i >= ntot) return;
    const float* src; int off;
    if (i < n0) { src = s0; off = i; }
    else if (i < n0 + n1) { src = s1; off = i - n0; }
    else if (i < n0 + n1 + n2) { src = s2; off = i - n0 - n1; }
    else { src = s3; off = i - n0 - n1 - n2; }
    float4 v = *reinterpret_cast<const float4*>(src + off);
    ushort4 o;
    o.x = f2bf(v.x); o.y = f2bf(v.y); o.z = f2bf(v.z); o.w = f2bf(v.w);
    *reinterpret_cast<ushort4*>(out + i) = o;
}

// ---------------- bf16 MFMA GEMM (m97 structure): 128x128 tile, BK=64 ----------------
// A: (Mpad x K) bf16. W: (N x K) bf16. Direct: C = act(A W^T + bias); split (gridDim.z>1):
// part[z][row][col] = partial over k-chunk z (no bias).
__global__ __launch_bounds__(256) void gemm_mfma(
    const unsigned short* __restrict__ A, const unsigned short* __restrict__ W,
    const float* __restrict__ bias, float* __restrict__ Cf, unsigned short* __restrict__ Cb,
    float* __restrict__ part, int M, int N, int K, int KC, int act)
{
    __shared__ unsigned short As[128 * 64];
    __shared__ unsigned short Bs[128 * 64];
    int tid = threadIdx.x;
    int m0 = blockIdx.y * 128, n0 = blockIdx.x * 128;
    int z = blockIdx.z;
    int kbeg = z * KC;
    int wid = tid >> 6, lane = tid & 63;
    int wm = wid >> 1, wn = wid & 1;
    int lr = lane & 15, lg = lane >> 4;
    int sr = tid >> 3, sc = (tid & 7) * 8;   // staging row/col

    f32x4 acc[4][4];
    #pragma unroll
    for (int mi = 0; mi < 4; ++mi)
        #pragma unroll
        for (int ni = 0; ni < 4; ++ni)
            acc[mi][ni] = (f32x4){0.f, 0.f, 0.f, 0.f};

    for (int k0 = kbeg; k0 < kbeg + KC; k0 += 64) {
        #pragma unroll
        for (int t = 0; t < 4; ++t)
            GLDS(&A[(size_t)(m0 + sr + t * 32) * K + k0 + sc], &As[(sr + t * 32) * 64 + sc]);
        #pragma unroll
        for (int t = 0; t < 4; ++t)
            GLDS(&W[(size_t)(n0 + sr + t * 32) * K + k0 + sc], &Bs[(sr + t * 32) * 64 + sc]);
        __syncthreads();
        #pragma unroll
        for (int ks = 0; ks < 64; ks += 32) {
            bf16x8 af[4], bfr[4];
            #pragma unroll
            for (int mi = 0; mi < 4; ++mi)
                af[mi] = *reinterpret_cast<const bf16x8*>(&As[(wm * 64 + mi * 16 + lr) * 64 + ks + lg * 8]);
            #pragma unroll
            for (int ni = 0; ni < 4; ++ni)
                bfr[ni] = *reinterpret_cast<const bf16x8*>(&Bs[(wn * 64 + ni * 16 + lr) * 64 + ks + lg * 8]);
            #pragma unroll
            for (int mi = 0; mi < 4; ++mi)
                #pragma unroll
                for (int ni = 0; ni < 4; ++ni)
                    acc[mi][ni] = __builtin_amdgcn_mfma_f32_16x16x32_bf16(af[mi], bfr[ni], acc[mi][ni], 0, 0, 0);
        }
        __syncthreads();
    }

    bool split = (gridDim.z > 1);
    #pragma unroll
    for (int mi = 0; mi < 4; ++mi) {
        #pragma unroll
        for (int rr = 0; rr < 4; ++rr) {
            int row = m0 + wm * 64 + mi * 16 + lg * 4 + rr;
            #pragma unroll
            for (int ni = 0; ni < 4; ++ni) {
                int col = n0 + wn * 64 + ni * 16 + lr;
                float v = acc[mi][ni][rr];
                if (split) {
                    part[((size_t)z * M + row) * N + col] = v;
                } else {
                    v += bias[col];
                    if (act) v = fmaxf(v, 0.f);
                    if (Cb) Cb[(size_t)row * N + col] = f2bf(v);
                    else    Cf[(size_t)row * N + col] = v;
                }
            }
        }
    }
}

// ---------------- residual(+partials+bias) add + LayerNorm + optional ximg-prepend ----------------
__global__ __launch_bounds__(256) void add_ln_fused(
    const float* __restrict__ h, const float* __restrict__ part, int nparts,
    const float* __restrict__ gb, const float* __restrict__ s, const float* __restrict__ bb,
    float* __restrict__ outf, unsigned short* __restrict__ outbf,
    const float* __restrict__ ximg, int tnew)
{
    int row = blockIdx.x;
    int t = row % TOK, b = row / TOK;
    int tid = threadIdx.x;
    if (t == tnew) {
        #pragma unroll
        for (int j = 0; j < 3; ++j) {
            int e = tid + j * 256;
            float v = ximg[b * E_ + e];
            if (outf)  outf[(size_t)row * E_ + e] = v;
            if (outbf) outbf[(size_t)row * E_ + e] = f2bf(v);
        }
        return;
    }
    __shared__ float sm[8];
    float v[3];
    #pragma unroll
    for (int j = 0; j < 3; ++j) {
        int e = tid + j * 256;
        float x = h[(size_t)row * E_ + e];
        for (int p = 0; p < nparts; ++p) x += part[((size_t)p * MPAD + row) * E_ + e];
        if (nparts) x += gb[e];
        v[j] = x;
    }
    float sum = v[0] + v[1] + v[2];
    #pragma unroll
    for (int o = 32; o >= 1; o >>= 1) sum += __shfl_xor(sum, o);
    int wid = tid >> 6, lane = tid & 63;
    if (lane == 0) sm[wid] = sum;
    __syncthreads();
    if (tid == 0) sm[0] = sm[0] + sm[1] + sm[2] + sm[3];
    __syncthreads();
    float mu = sm[0] * (1.0f / E_);
    __syncthreads();
    float sq = 0.f;
    #pragma unroll
    for (int j = 0; j < 3; ++j) { float d = v[j] - mu; sq += d * d; }
    #pragma unroll
    for (int o = 32; o >= 1; o >>= 1) sq += __shfl_xor(sq, o);
    if (lane == 0) sm[wid] = sq;
    __syncthreads();
    if (tid == 0) sm[0] = sm[0] + sm[1] + sm[2] + sm[3];
    __syncthreads();
    float rstd = rsqrtf(sm[0] * (1.0f / E_) + 1e-5f);
    #pragma unroll
    for (int j = 0; j < 3; ++j) {
        int e = tid + j * 256;
        float r = (v[j] - mu) * rstd * s[e] + bb[e];
        if (outf)  outf[(size_t)row * E_ + e] = r;
        if (outbf) outbf[(size_t)row * E_ + e] = f2bf(r);
    }
}

// ---------------- attention: one block per (b, head), tokens [start, 62), bf16 out ----------------
__global__ __launch_bounds__(256) void attn_kernel(
    const float* __restrict__ qkv, unsigned short* __restrict__ obf, int start)
{
    int h = blockIdx.x, b = blockIdx.y;
    int S = TOK - start;
    int tid = threadIdx.x;
    int row = tid >> 6, lane = tid & 63;
    __shared__ float klds[64][65];
    __shared__ float vlds[64][65];
    __shared__ float qlds[4][64];
    __shared__ float plds[4][64];
    const size_t basebh = (size_t)b * TOK * 2304 + h * 64;

    for (int idx = tid; idx < S * 64; idx += 256) {
        int j = idx >> 6, d = idx & 63;
        klds[j][d] = qkv[basebh + (size_t)(start + j) * 2304 + 768 + d];
        vlds[j][d] = qkv[basebh + (size_t)(start + j) * 2304 + 1536 + d];
    }
    __syncthreads();

    for (int qi0 = start; qi0 < TOK; qi0 += 4) {
        int qi = qi0 + row;
        qlds[row][lane] = (qi < TOK) ? qkv[basebh + (size_t)qi * 2304 + lane] : 0.f;
        __syncthreads();
        float sv = -1e30f;
        if (lane < S && qi < TOK) {
            float acc = 0.f;
            #pragma unroll
            for (int d = 0; d < 64; ++d) acc += qlds[row][d] * klds[lane][d];
            sv = acc * 0.125f;
        }
        float m = sv;
        #pragma unroll
        for (int o = 32; o >= 1; o >>= 1) m = fmaxf(m, __shfl_xor(m, o));
        float p = expf(sv - m);
        float l = p;
        #pragma unroll
        for (int o = 32; o >= 1; o >>= 1) l += __shfl_xor(l, o);
        p /= l;
        plds[row][lane] = p;
        __syncthreads();
        float o_acc = 0.f;
        for (int j = 0; j < S; ++j) o_acc += plds[row][j] * vlds[j][lane];
        if (qi < TOK) obf[(size_t)(b * TOK + qi) * E_ + h * 64 + lane] = f2bf(o_acc);
        __syncthreads();
    }
}

// ---------------- small glue kernels ----------------
__global__ __launch_bounds__(256) void mean_kernel(const float* __restrict__ x, float* __restrict__ xmean)
{
    int bc = blockIdx.x;
    const float* p = x + (size_t)bc * IMG_ * IMG_;
    float s = 0.f;
    for (int i = threadIdx.x; i < IMG_ * IMG_; i += 256) s += p[i];
    #pragma unroll
    for (int o = 32; o >= 1; o >>= 1) s += __shfl_xor(s, o);
    __shared__ float sm[4];
    int wid = threadIdx.x >> 6, lane = threadIdx.x & 63;
    if (lane == 0) sm[wid] = s;
    __syncthreads();
    if (threadIdx.x == 0) xmean[bc] = (sm[0] + sm[1] + sm[2] + sm[3]) / (float)(IMG_ * IMG_);
}

__global__ void ximg_kernel(const float* __restrict__ xmean, const float* __restrict__ Wbb,
                            const float* __restrict__ bbb, float* __restrict__ ximg)
{
    int idx = blockIdx.x * 256 + threadIdx.x;
    if (idx >= B_ * E_) return;
    int e = idx % E_, b = idx / E_;
    ximg[idx] = xmean[b * 3 + 0] * Wbb[0 * E_ + e]
              + xmean[b * 3 + 1] * Wbb[1 * E_ + e]
              + xmean[b * 3 + 2] * Wbb[2 * E_ + e] + bbb[e];
}

__global__ void im2col_kernel(const float* __restrict__ x, unsigned short* __restrict__ Pm)
{
    int idx = blockIdx.x * 256 + threadIdx.x;
    if (idx >= PMROWS * 3072) return;
    int k = idx % 3072;
    int rowp = idx / 3072;
    int n = rowp % NPATCH, b = rowp / NPATCH;
    int i = n / G_, j = n % G_;
    int c = k >> 10;
    int r = k & 1023;
    int p = r >> 5, q = r & 31;
    Pm[idx] = f2bf(x[(((size_t)b * C_ + c) * IMG_ + i * P_ + p) * IMG_ + j * P_ + q]);
}

// build h0: sums 3 patch-embed partials (+bp), adds pos, writes f32 + bf16
__global__ void build_h0_kernel(const float* __restrict__ part, const float* __restrict__ bp,
                                const float* __restrict__ cls, const float* __restrict__ pos,
                                float* __restrict__ hbuf, unsigned short* __restrict__ hbf)
{
    int idx = blockIdx.x * 256 + threadIdx.x;
    if (idx >= MROWS * E_) return;
    int e = idx % E_;
    int t = (idx / E_) % TOK;
    int b = idx / (E_ * TOK);
    float v = 0.f;
    if (t >= 12) {
        int sseq = t - 12;
        float base;
        if (sseq == 0) base = cls[e];
        else {
            int prow = b * NPATCH + (sseq - 1);
            base = bp[e];
            #pragma unroll
            for (int s = 0; s < 3; ++s) base += part[((size_t)s * PMPAD + prow) * E_ + e];
        }
        v = base + pos[sseq * E_ + e];
    }
    hbuf[idx] = v;
    hbf[idx] = f2bf(v);
}

// ---------------- head1: MFMA streaming, split-K=31, fp32 W converted in-register ----------------
__global__ __launch_bounds__(256) void head1_mfma(
    const unsigned short* __restrict__ hfb, const float* __restrict__ Wh1,
    float* __restrict__ part)
{
    int tid = threadIdx.x;
    int wid = tid >> 6, lane = tid & 63;
    int lr = lane & 15, lg = lane >> 4;
    int n0 = blockIdx.x * 64 + wid * 16;
    int kc = blockIdx.y;
    f32x4 acc0 = (f32x4){0.f, 0.f, 0.f, 0.f};
    f32x4 acc1 = (f32x4){0.f, 0.f, 0.f, 0.f};
    const float* wrow = Wh1 + (size_t)(n0 + lr) * FLAT_ + (size_t)kc * HKC + lg * 8;
    const unsigned short* a0 = hfb + (size_t)lr * FLAT_ + (size_t)kc * HKC + lg * 8;
    const unsigned short* a1 = hfb + (size_t)(16 + lr) * FLAT_ + (size_t)kc * HKC + lg * 8;
    #pragma unroll 4
    for (int k = 0; k < HKC; k += 32) {
        float4 w0 = *reinterpret_cast<const float4*>(wrow + k);
        float4 w1 = *reinterpret_cast<const float4*>(wrow + k + 4);
        uint4 u;
        u.x = cvtpk(w0.x, w0.y); u.y = cvtpk(w0.z, w0.w);
        u.z = cvtpk(w1.x, w1.y); u.w = cvtpk(w1.z, w1.w);
        bf16x8 bw = __builtin_bit_cast(bf16x8, u);
        bf16x8 af0 = *reinterpret_cast<const bf16x8*>(a0 + k);
        bf16x8 af1 = *reinterpret_cast<const bf16x8*>(a1 + k);
        acc0 = __builtin_amdgcn_mfma_f32_16x16x32_bf16(af0, bw, acc0, 0, 0, 0);
        acc1 = __builtin_amdgcn_mfma_f32_16x16x32_bf16(af1, bw, acc1, 0, 0, 0);
    }
    int n = n0 + lr;
    #pragma unroll
    for (int rr = 0; rr < 4; ++rr) {
        int m = lg * 4 + rr;
        part[((size_t)kc * B_ + m) * MLP_ + n] = acc0[rr];
        part[((size_t)kc * B_ + 16 + m) * MLP_ + n] = acc1[rr];
    }
}

__global__ void head1_fin_kernel(const float* __restrict__ part, const float* __restrict__ bh1,
                                 float* __restrict__ out1)
{
    int idx = blockIdx.x * 256 + threadIdx.x;
    if (idx >= B_ * MLP_) return;
    int n = idx % MLP_, b = idx / MLP_;
    float s = bh1[n];
    for (int kc = 0; kc < HKS; ++kc) s += part[((size_t)kc * B_ + b) * MLP_ + n];
    out1[idx] = 0.5f * s * (1.0f + erff(s * 0.70710678118654752f));
}

__global__ __launch_bounds__(256) void head2_kernel(const float* __restrict__ out1,
                                                    const float* __restrict__ Wh2,
                                                    const float* __restrict__ bh2,
                                                    float* __restrict__ out)
{
    int bc = blockIdx.x;
    int b = bc / NC_, c = bc % NC_;
    float s = 0.f;
    for (int nn = threadIdx.x; nn < MLP_; nn += 256) s += out1[(size_t)b * MLP_ + nn] * Wh2[(size_t)c * MLP_ + nn];
    #pragma unroll
    for (int o = 32; o >= 1; o >>= 1) s += __shfl_xor(s, o);
    __shared__ float sm[4];
    int wid = threadIdx.x >> 6, lane = threadIdx.x & 63;
    if (lane == 0) sm[wid] = s;
    __syncthreads();
    if (threadIdx.x == 0) out[bc] = sm[0] + sm[1] + sm[2] + sm[3] + bh2[c];
}

// ---------------- driver ----------------
extern "C" void kernel_launch(void* const* d_in, const int* in_sizes, int n_in,
                              void* d_out, int out_size, void* d_ws, size_t ws_size,
                              hipStream_t stream)
{
    (void)in_sizes; (void)n_in; (void)out_size; (void)ws_size;
    const float* x    = (const float*)d_in[0];
    const float* Wp   = (const float*)d_in[1];
    const float* bp   = (const float*)d_in[2];
    const float* cls  = (const float*)d_in[3];
    const float* pos  = (const float*)d_in[4];
    const float* Wbb  = (const float*)d_in[5];
    const float* bbb  = (const float*)d_in[6];
    const float* Wqkv = (const float*)d_in[7];
    const float* bqkv = (const float*)d_in[8];
    const float* Wo   = (const float*)d_in[9];
    const float* bo   = (const float*)d_in[10];
    const float* ln1s = (const float*)d_in[11];
    const float* ln1b = (const float*)d_in[12];
    const float* W1   = (const float*)d_in[13];
    const float* b1   = (const float*)d_in[14];
    const float* W2   = (const float*)d_in[15];
    const float* b2   = (const float*)d_in[16];
    const float* ln2s = (const float*)d_in[17];
    const float* ln2b = (const float*)d_in[18];
    const float* lnfs = (const float*)d_in[19];
    const float* lnfb = (const float*)d_in[20];
    const float* Wh1  = (const float*)d_in[21];
    const float* bh1  = (const float*)d_in[22];
    const float* Wh2  = (const float*)d_in[23];
    const float* bh2  = (const float*)d_in[24];
    float* out = (float*)d_out;

    float* ws = (float*)d_ws;
    size_t off = 0;
    float* hbuf   = ws + off; off += (size_t)MROWS * E_;           // f32 residual
    float* qkvbuf = ws + off; off += (size_t)MPAD * 2304;          // qkv f32 / split-K partials / head part
    unsigned short* hbf  = (unsigned short*)(ws + off); off += (size_t)MPAD * E_ / 2;
    unsigned short* obf  = (unsigned short*)(ws + off); off += (size_t)MPAD * E_ / 2;
    unsigned short* ffbf = (unsigned short*)(ws + off); off += (size_t)MPAD * DFF_ / 2;  // also Pmbf
    unsigned short* wbf  = (unsigned short*)(ws + off); off += (size_t)WTOT / 2 + 64;
    unsigned short* hfb  = (unsigned short*)(ws + off); off += (size_t)MROWS * E_ / 2;
    float* ximg  = ws + off; off += B_ * E_;
    float* xmean = ws + off; off += 128;
    float* out1  = ws + off; off += B_ * MLP_;

    float* part = qkvbuf;                 // aliases qkv buffer (dead when partials live)
    unsigned short* Pmbf = ffbf;

    // backbone token
    mean_kernel<<<B_ * C_, 256, 0, stream>>>(x, xmean);
    ximg_kernel<<<(B_ * E_ + 255) / 256, 256, 0, stream>>>(xmean, Wbb, bbb, ximg);

    // patch embedding: im2col -> bf16 gemm (split-K=3) -> h0
    im2col_kernel<<<(PMROWS * 3072 + 255) / 256, 256, 0, stream>>>(x, Pmbf);
    cvt4_kernel<<<(768 * 3072) / 1024, 256, 0, stream>>>(Wp, 768 * 3072, nullptr, 0, nullptr, 0, nullptr, 0, wbf);
    gemm_mfma<<<dim3(E_ / 128, PMPAD / 128, 3), 256, 0, stream>>>(
        Pmbf, wbf, nullptr, nullptr, nullptr, part, PMPAD, E_, 3072, 1024, 0);
    build_h0_kernel<<<(MROWS * E_ + 255) / 256, 256, 0, stream>>>(part, bp, cls, pos, hbuf, hbf);

    for (int i = 0; i < L_; ++i) {
        int start = 12 - i;
        cvt4_kernel<<<WTOT / 1024, 256, 0, stream>>>(
            Wqkv + (size_t)i * WQKV_SZ, WQKV_SZ, Wo + (size_t)i * WO_SZ, WO_SZ,
            W1 + (size_t)i * W1_SZ, W1_SZ, W2 + (size_t)i * W2_SZ, W2_SZ, wbf);
        // qkv: direct f32 out
        gemm_mfma<<<dim3(2304 / 128, MPAD / 128, 1), 256, 0, stream>>>(
            hbf, wbf, bqkv + i * 2304, qkvbuf, nullptr, nullptr, MPAD, 2304, E_, E_, 0);
        attn_kernel<<<dim3(NH_, B_), 256, 0, stream>>>(qkvbuf, obf, start);
        // proj: split-K=3 partials (aliases qkvbuf, attn already consumed it)
        gemm_mfma<<<dim3(E_ / 128, MPAD / 128, 3), 256, 0, stream>>>(
            obf, wbf + WQKV_SZ, nullptr, nullptr, nullptr, part, MPAD, E_, E_, 256, 0);
        add_ln_fused<<<MROWS, 256, 0, stream>>>(
            hbuf, part, 3, bo + i * E_, ln1s + i * E_, ln1b + i * E_, hbuf, hbf, nullptr, -1);
        // ffn1: direct bf16 out + relu
        gemm_mfma<<<dim3(DFF_ / 128, MPAD / 128, 1), 256, 0, stream>>>(
            hbf, wbf + WQKV_SZ + WO_SZ, b1 + i * DFF_, nullptr, ffbf, nullptr, MPAD, DFF_, E_, E_, 1);
        // ffn2: split-K=3 partials
        gemm_mfma<<<dim3(E_ / 128, MPAD / 128, 3), 256, 0, stream>>>(
            ffbf, wbf + WQKV_SZ + WO_SZ + W1_SZ, nullptr, nullptr, nullptr, part, MPAD, E_, DFF_, 1024, 0);
        add_ln_fused<<<MROWS, 256, 0, stream>>>(
            hbuf, part, 3, b2 + i * E_, ln2s + i * E_, ln2b + i * E_, hbuf, hbf, ximg, 11 - i);
    }

    // final LN (bf16 only) + head
    add_ln_fused<<<MROWS, 256, 0, stream>>>(
        hbuf, nullptr, 0, nullptr, lnfs, lnfb, nullptr, hfb, nullptr, -1);
    head1_mfma<<<dim3(MLP_ / 64, HKS), 256, 0, stream>>>(hfb, Wh1, part);
    head1_fin_kernel<<<(B_ * MLP_ + 255) / 256, 256, 0, stream>>>(part, bh1, out1);
    head2_kernel<<<B_ * NC_, 256, 0, stream>>>(out1, Wh2, bh2, out);
}

// Round 4
// 1979.906 us; speedup vs baseline: 3.8698x; 1.1898x over previous
//
#include <hip/hip_runtime.h>
#include <math.h>

#define B_ 32
#define C_ 3
#define IMG_ 224
#define P_ 32
#define G_ 7
#define NPATCH 49
#define E_ 768
#define NH_ 12
#define L_ 12
#define DFF_ 3072
#define MLP_ 2048
#define NC_ 5
#define TOK 62
#define MROWS (B_*TOK)      // 1984
#define FLAT_ (TOK*E_)      // 47616
#define MPAD 2048
#define PMROWS (B_*NPATCH)  // 1568
#define PMPAD 1664          // 13*128
#define HKS 31              // head split-K
#define HKC (FLAT_/HKS)     // 1536

// per-layer weight sizes (elements)
#define WQKV_SZ (2304*768)
#define WO_SZ   (768*768)
#define W1_SZ   (3072*768)
#define W2_SZ   (768*3072)

typedef __bf16 bf16x8 __attribute__((ext_vector_type(8)));
typedef float f32x4 __attribute__((ext_vector_type(4)));

__device__ inline unsigned short f2bf(float f) {
    unsigned u = __float_as_uint(f);
    u += 0x7FFF + ((u >> 16) & 1);
    return (unsigned short)(u >> 16);
}

__device__ inline unsigned cvtpk(float lo, float hi) {
    unsigned r;
    asm("v_cvt_pk_bf16_f32 %0, %1, %2" : "=v"(r) : "v"(lo), "v"(hi));
    return r;
}

#define GLDS(gsrc, ldst) __builtin_amdgcn_global_load_lds( \
    (__attribute__((address_space(1))) const void*)(gsrc), \
    (__attribute__((address_space(3))) void*)(ldst), 16, 0, 0)

// ---------------- fp32 -> bf16 streaming conversion ----------------
__global__ __launch_bounds__(256) void cvt_kernel(
    const float* __restrict__ in, unsigned short* __restrict__ out, int n4)
{
    int i = blockIdx.x * 256 + threadIdx.x;
    if (i >= n4) return;
    float4 v = reinterpret_cast<const float4*>(in)[i];
    ushort4 o;
    o.x = f2bf(v.x); o.y = f2bf(v.y); o.z = f2bf(v.z); o.w = f2bf(v.w);
    reinterpret_cast<ushort4*>(out)[i] = o;
}

// ---------------- bf16 MFMA GEMM (m97 structure): 128x128 tile, BK=64 ----------------
__global__ __launch_bounds__(256) void gemm_mfma(
    const unsigned short* __restrict__ A, const unsigned short* __restrict__ W,
    const float* __restrict__ bias, float* __restrict__ Cf, unsigned short* __restrict__ Cb,
    float* __restrict__ part, int M, int N, int K, int KC, int act)
{
    __shared__ unsigned short As[128 * 64];
    __shared__ unsigned short Bs[128 * 64];
    int tid = threadIdx.x;
    int m0 = blockIdx.y * 128, n0 = blockIdx.x * 128;
    int z = blockIdx.z;
    int kbeg = z * KC;
    int wid = tid >> 6, lane = tid & 63;
    int wm = wid >> 1, wn = wid & 1;
    int lr = lane & 15, lg = lane >> 4;
    int sr = tid >> 3, sc = (tid & 7) * 8;

    f32x4 acc[4][4];
    #pragma unroll
    for (int mi = 0; mi < 4; ++mi)
        #pragma unroll
        for (int ni = 0; ni < 4; ++ni)
            acc[mi][ni] = (f32x4){0.f, 0.f, 0.f, 0.f};

    for (int k0 = kbeg; k0 < kbeg + KC; k0 += 64) {
        #pragma unroll
        for (int t = 0; t < 4; ++t)
            GLDS(&A[(size_t)(m0 + sr + t * 32) * K + k0 + sc], &As[(sr + t * 32) * 64 + sc]);
        #pragma unroll
        for (int t = 0; t < 4; ++t)
            GLDS(&W[(size_t)(n0 + sr + t * 32) * K + k0 + sc], &Bs[(sr + t * 32) * 64 + sc]);
        __syncthreads();
        #pragma unroll
        for (int ks = 0; ks < 64; ks += 32) {
            bf16x8 af[4], bfr[4];
            #pragma unroll
            for (int mi = 0; mi < 4; ++mi)
                af[mi] = *reinterpret_cast<const bf16x8*>(&As[(wm * 64 + mi * 16 + lr) * 64 + ks + lg * 8]);
            #pragma unroll
            for (int ni = 0; ni < 4; ++ni)
                bfr[ni] = *reinterpret_cast<const bf16x8*>(&Bs[(wn * 64 + ni * 16 + lr) * 64 + ks + lg * 8]);
            #pragma unroll
            for (int mi = 0; mi < 4; ++mi)
                #pragma unroll
                for (int ni = 0; ni < 4; ++ni)
                    acc[mi][ni] = __builtin_amdgcn_mfma_f32_16x16x32_bf16(af[mi], bfr[ni], acc[mi][ni], 0, 0, 0);
        }
        __syncthreads();
    }

    bool split = (gridDim.z > 1);
    #pragma unroll
    for (int mi = 0; mi < 4; ++mi) {
        #pragma unroll
        for (int rr = 0; rr < 4; ++rr) {
            int row = m0 + wm * 64 + mi * 16 + lg * 4 + rr;
            #pragma unroll
            for (int ni = 0; ni < 4; ++ni) {
                int col = n0 + wn * 64 + ni * 16 + lr;
                float v = acc[mi][ni][rr];
                if (split) {
                    part[((size_t)z * M + row) * N + col] = v;
                } else {
                    v += bias[col];
                    if (act) v = fmaxf(v, 0.f);
                    if (Cb) Cb[(size_t)row * N + col] = f2bf(v);
                    else    Cf[(size_t)row * N + col] = v;
                }
            }
        }
    }
}

// ---------------- residual(+partials+bias) add + LayerNorm + optional ximg-prepend ----------------
__global__ __launch_bounds__(256) void add_ln_fused(
    const float* __restrict__ h, const float* __restrict__ part, int nparts,
    const float* __restrict__ gb, const float* __restrict__ s, const float* __restrict__ bb,
    float* __restrict__ outf, unsigned short* __restrict__ outbf,
    const float* __restrict__ ximg, int tnew)
{
    int row = blockIdx.x;
    int t = row % TOK, b = row / TOK;
    int tid = threadIdx.x;
    if (t == tnew) {
        #pragma unroll
        for (int j = 0; j < 3; ++j) {
            int e = tid + j * 256;
            float v = ximg[b * E_ + e];
            if (outf)  outf[(size_t)row * E_ + e] = v;
            if (outbf) outbf[(size_t)row * E_ + e] = f2bf(v);
        }
        return;
    }
    __shared__ float sm[8];
    float v[3];
    #pragma unroll
    for (int j = 0; j < 3; ++j) {
        int e = tid + j * 256;
        float x = h[(size_t)row * E_ + e];
        for (int p = 0; p < nparts; ++p) x += part[((size_t)p * MPAD + row) * E_ + e];
        if (nparts) x += gb[e];
        v[j] = x;
    }
    float sum = v[0] + v[1] + v[2];
    #pragma unroll
    for (int o = 32; o >= 1; o >>= 1) sum += __shfl_xor(sum, o);
    int wid = tid >> 6, lane = tid & 63;
    if (lane == 0) sm[wid] = sum;
    __syncthreads();
    if (tid == 0) sm[0] = sm[0] + sm[1] + sm[2] + sm[3];
    __syncthreads();
    float mu = sm[0] * (1.0f / E_);
    __syncthreads();
    float sq = 0.f;
    #pragma unroll
    for (int j = 0; j < 3; ++j) { float d = v[j] - mu; sq += d * d; }
    #pragma unroll
    for (int o = 32; o >= 1; o >>= 1) sq += __shfl_xor(sq, o);
    if (lane == 0) sm[wid] = sq;
    __syncthreads();
    if (tid == 0) sm[0] = sm[0] + sm[1] + sm[2] + sm[3];
    __syncthreads();
    float rstd = rsqrtf(sm[0] * (1.0f / E_) + 1e-5f);
    #pragma unroll
    for (int j = 0; j < 3; ++j) {
        int e = tid + j * 256;
        float r = (v[j] - mu) * rstd * s[e] + bb[e];
        if (outf)  outf[(size_t)row * E_ + e] = r;
        if (outbf) outbf[(size_t)row * E_ + e] = f2bf(r);
    }
}

// ---------------- MFMA attention: one block per (b, head); 64-slot K/Q tiles, bf16 ----------------
// qkv is bf16 [MPAD][2304]. Tokens [start,62); S = 62-start <= 62 <= 64.
__global__ __launch_bounds__(256) void attn_mfma(
    const unsigned short* __restrict__ qkv, unsigned short* __restrict__ obf, int start)
{
    int h = blockIdx.x, b = blockIdx.y;
    int S = TOK - start;
    int tid = threadIdx.x;
    int wid = tid >> 6, lane = tid & 63;
    int lr = lane & 15, lg = lane >> 4;

    __shared__ unsigned short Qs[64 * 64];      // XOR-chunk swizzled
    __shared__ unsigned short Ks[64 * 64];      // XOR-chunk swizzled
    __shared__ unsigned short VT[64 * 72];      // V transposed [d][k], padded
    __shared__ unsigned short Ps[4][16 * 72];   // per-wave P [q][k], padded

    const unsigned short* base = qkv + ((size_t)(b * TOK + start)) * 2304 + h * 64;

    // stage Q, K via global_load_lds; source pre-swizzled so LDS chunk (row, c)
    // holds data chunk c ^ (row&7)  (chunk = 16B = 8 bf16)
    #pragma unroll
    for (int t = 0; t < 2; ++t) {
        int r0 = wid * 16 + t * 8;
        int row = r0 + (lane >> 3);
        int sc = ((lane & 7) ^ (row & 7)) * 8;
        GLDS(base + (size_t)row * 2304 + sc,       &Qs[r0 * 64]);
        GLDS(base + (size_t)row * 2304 + 768 + sc, &Ks[r0 * 64]);
    }
    // stage V transposed: VT[d][k] = V[k][d]
    #pragma unroll
    for (int it = 0; it < 8; ++it) {
        int pi = it * 256 + tid;          // 0..2047
        int k = pi >> 5;
        int d0 = (pi & 31) * 2;
        unsigned u = *reinterpret_cast<const unsigned*>(base + (size_t)k * 2304 + 1536 + d0);
        VT[d0 * 72 + k] = (unsigned short)(u & 0xffff);
        VT[(d0 + 1) * 72 + k] = (unsigned short)(u >> 16);
    }
    __syncthreads();

    // QK^T (swapped): S^T[key][q] = mfma(K, Q); this wave's q-slots = wid*16 .. +15
    f32x4 st[4];
    #pragma unroll
    for (int mt = 0; mt < 4; ++mt) st[mt] = (f32x4){0.f, 0.f, 0.f, 0.f};
    bf16x8 qb[2];
    #pragma unroll
    for (int ks = 0; ks < 2; ++ks) {
        int qrow = wid * 16 + lr;
        int ck = ((ks * 4 + lg) ^ (qrow & 7)) * 8;
        qb[ks] = *reinterpret_cast<const bf16x8*>(&Qs[qrow * 64 + ck]);
    }
    #pragma unroll
    for (int mt = 0; mt < 4; ++mt) {
        #pragma unroll
        for (int ks = 0; ks < 2; ++ks) {
            int krow = mt * 16 + lr;
            int ck = ((ks * 4 + lg) ^ (krow & 7)) * 8;
            bf16x8 kb = *reinterpret_cast<const bf16x8*>(&Ks[krow * 64 + ck]);
            st[mt] = __builtin_amdgcn_mfma_f32_16x16x32_bf16(kb, qb[ks], st[mt], 0, 0, 0);
        }
    }

    // softmax over keys (column q = lane&15 within this wave's 16 q's)
    float mx = -1e30f;
    #pragma unroll
    for (int mt = 0; mt < 4; ++mt)
        #pragma unroll
        for (int rr = 0; rr < 4; ++rr) {
            int k = mt * 16 + lg * 4 + rr;
            float v = st[mt][rr] * 0.125f;
            v = (k < S) ? v : -1e30f;
            st[mt][rr] = v;
            mx = fmaxf(mx, v);
        }
    mx = fmaxf(mx, __shfl_xor(mx, 16));
    mx = fmaxf(mx, __shfl_xor(mx, 32));
    float sum = 0.f;
    #pragma unroll
    for (int mt = 0; mt < 4; ++mt)
        #pragma unroll
        for (int rr = 0; rr < 4; ++rr) {
            float p = __expf(st[mt][rr] - mx);
            st[mt][rr] = p;
            sum += p;
        }
    sum += __shfl_xor(sum, 16);
    sum += __shfl_xor(sum, 32);
    float inv = 1.0f / sum;

    // pack P (bf16) into per-wave LDS: Ps[wid][q=lr][k]
    #pragma unroll
    for (int mt = 0; mt < 4; ++mt) {
        int k0 = mt * 16 + lg * 4;
        unsigned u0 = cvtpk(st[mt][0] * inv, st[mt][1] * inv);
        unsigned u1 = cvtpk(st[mt][2] * inv, st[mt][3] * inv);
        *reinterpret_cast<unsigned*>(&Ps[wid][lr * 72 + k0]) = u0;
        *reinterpret_cast<unsigned*>(&Ps[wid][lr * 72 + k0 + 2]) = u1;
    }
    __syncthreads();

    // PV: O[q][d] = sum_k P[q][k] * VT[d][k]
    f32x4 oa[4];
    #pragma unroll
    for (int nt = 0; nt < 4; ++nt) oa[nt] = (f32x4){0.f, 0.f, 0.f, 0.f};
    #pragma unroll
    for (int ks = 0; ks < 2; ++ks) {
        bf16x8 pa = *reinterpret_cast<const bf16x8*>(&Ps[wid][lr * 72 + ks * 32 + lg * 8]);
        #pragma unroll
        for (int nt = 0; nt < 4; ++nt) {
            bf16x8 vb = *reinterpret_cast<const bf16x8*>(&VT[(nt * 16 + lr) * 72 + ks * 32 + lg * 8]);
            oa[nt] = __builtin_amdgcn_mfma_f32_16x16x32_bf16(pa, vb, oa[nt], 0, 0, 0);
        }
    }

    // store: O row q = wid*16 + lg*4 + rr, col d = nt*16 + lr
    #pragma unroll
    for (int nt = 0; nt < 4; ++nt)
        #pragma unroll
        for (int rr = 0; rr < 4; ++rr) {
            int qs = wid * 16 + lg * 4 + rr;
            if (qs < S)
                obf[((size_t)(b * TOK + start + qs)) * E_ + h * 64 + nt * 16 + lr] = f2bf(oa[nt][rr]);
        }
}

// ---------------- small glue kernels ----------------
__global__ __launch_bounds__(256) void mean_kernel(const float* __restrict__ x, float* __restrict__ xmean)
{
    int bc = blockIdx.x;
    const float* p = x + (size_t)bc * IMG_ * IMG_;
    float s = 0.f;
    for (int i = threadIdx.x; i < IMG_ * IMG_; i += 256) s += p[i];
    #pragma unroll
    for (int o = 32; o >= 1; o >>= 1) s += __shfl_xor(s, o);
    __shared__ float sm[4];
    int wid = threadIdx.x >> 6, lane = threadIdx.x & 63;
    if (lane == 0) sm[wid] = s;
    __syncthreads();
    if (threadIdx.x == 0) xmean[bc] = (sm[0] + sm[1] + sm[2] + sm[3]) / (float)(IMG_ * IMG_);
}

__global__ void ximg_kernel(const float* __restrict__ xmean, const float* __restrict__ Wbb,
                            const float* __restrict__ bbb, float* __restrict__ ximg)
{
    int idx = blockIdx.x * 256 + threadIdx.x;
    if (idx >= B_ * E_) return;
    int e = idx % E_, b = idx / E_;
    ximg[idx] = xmean[b * 3 + 0] * Wbb[0 * E_ + e]
              + xmean[b * 3 + 1] * Wbb[1 * E_ + e]
              + xmean[b * 3 + 2] * Wbb[2 * E_ + e] + bbb[e];
}

__global__ void im2col_kernel(const float* __restrict__ x, unsigned short* __restrict__ Pm)
{
    int idx = blockIdx.x * 256 + threadIdx.x;
    if (idx >= PMROWS * 3072) return;
    int k = idx % 3072;
    int rowp = idx / 3072;
    int n = rowp % NPATCH, b = rowp / NPATCH;
    int i = n / G_, j = n % G_;
    int c = k >> 10;
    int r = k & 1023;
    int p = r >> 5, q = r & 31;
    Pm[idx] = f2bf(x[(((size_t)b * C_ + c) * IMG_ + i * P_ + p) * IMG_ + j * P_ + q]);
}

__global__ void build_h0_kernel(const float* __restrict__ part, const float* __restrict__ bp,
                                const float* __restrict__ cls, const float* __restrict__ pos,
                                float* __restrict__ hbuf, unsigned short* __restrict__ hbf)
{
    int idx = blockIdx.x * 256 + threadIdx.x;
    if (idx >= MROWS * E_) return;
    int e = idx % E_;
    int t = (idx / E_) % TOK;
    int b = idx / (E_ * TOK);
    float v = 0.f;
    if (t >= 12) {
        int sseq = t - 12;
        float base;
        if (sseq == 0) base = cls[e];
        else {
            int prow = b * NPATCH + (sseq - 1);
            base = bp[e];
            #pragma unroll
            for (int s = 0; s < 3; ++s) base += part[((size_t)s * PMPAD + prow) * E_ + e];
        }
        v = base + pos[sseq * E_ + e];
    }
    hbuf[idx] = v;
    hbf[idx] = f2bf(v);
}

// ---------------- head1: MFMA streaming, split-K=31, fp32 W converted in-register ----------------
__global__ __launch_bounds__(256) void head1_mfma(
    const unsigned short* __restrict__ hfb, const float* __restrict__ Wh1,
    float* __restrict__ part)
{
    int tid = threadIdx.x;
    int wid = tid >> 6, lane = tid & 63;
    int lr = lane & 15, lg = lane >> 4;
    int n0 = blockIdx.x * 64 + wid * 16;
    int kc = blockIdx.y;
    f32x4 acc0 = (f32x4){0.f, 0.f, 0.f, 0.f};
    f32x4 acc1 = (f32x4){0.f, 0.f, 0.f, 0.f};
    const float* wrow = Wh1 + (size_t)(n0 + lr) * FLAT_ + (size_t)kc * HKC + lg * 8;
    const unsigned short* a0 = hfb + (size_t)lr * FLAT_ + (size_t)kc * HKC + lg * 8;
    const unsigned short* a1 = hfb + (size_t)(16 + lr) * FLAT_ + (size_t)kc * HKC + lg * 8;
    #pragma unroll 4
    for (int k = 0; k < HKC; k += 32) {
        float4 w0 = *reinterpret_cast<const float4*>(wrow + k);
        float4 w1 = *reinterpret_cast<const float4*>(wrow + k + 4);
        uint4 u;
        u.x = cvtpk(w0.x, w0.y); u.y = cvtpk(w0.z, w0.w);
        u.z = cvtpk(w1.x, w1.y); u.w = cvtpk(w1.z, w1.w);
        bf16x8 bw = __builtin_bit_cast(bf16x8, u);
        bf16x8 af0 = *reinterpret_cast<const bf16x8*>(a0 + k);
        bf16x8 af1 = *reinterpret_cast<const bf16x8*>(a1 + k);
        acc0 = __builtin_amdgcn_mfma_f32_16x16x32_bf16(af0, bw, acc0, 0, 0, 0);
        acc1 = __builtin_amdgcn_mfma_f32_16x16x32_bf16(af1, bw, acc1, 0, 0, 0);
    }
    int n = n0 + lr;
    #pragma unroll
    for (int rr = 0; rr < 4; ++rr) {
        int m = lg * 4 + rr;
        part[((size_t)kc * B_ + m) * MLP_ + n] = acc0[rr];
        part[((size_t)kc * B_ + 16 + m) * MLP_ + n] = acc1[rr];
    }
}

__global__ void head1_fin_kernel(const float* __restrict__ part, const float* __restrict__ bh1,
                                 float* __restrict__ out1)
{
    int idx = blockIdx.x * 256 + threadIdx.x;
    if (idx >= B_ * MLP_) return;
    int n = idx % MLP_, b = idx / MLP_;
    float s = bh1[n];
    for (int kc = 0; kc < HKS; ++kc) s += part[((size_t)kc * B_ + b) * MLP_ + n];
    out1[idx] = 0.5f * s * (1.0f + erff(s * 0.70710678118654752f));
}

__global__ __launch_bounds__(256) void head2_kernel(const float* __restrict__ out1,
                                                    const float* __restrict__ Wh2,
                                                    const float* __restrict__ bh2,
                                                    float* __restrict__ out)
{
    int bc = blockIdx.x;
    int b = bc / NC_, c = bc % NC_;
    float s = 0.f;
    for (int nn = threadIdx.x; nn < MLP_; nn += 256) s += out1[(size_t)b * MLP_ + nn] * Wh2[(size_t)c * MLP_ + nn];
    #pragma unroll
    for (int o = 32; o >= 1; o >>= 1) s += __shfl_xor(s, o);
    __shared__ float sm[4];
    int wid = threadIdx.x >> 6, lane = threadIdx.x & 63;
    if (lane == 0) sm[wid] = s;
    __syncthreads();
    if (threadIdx.x == 0) out[bc] = sm[0] + sm[1] + sm[2] + sm[3] + bh2[c];
}

// ---------------- driver ----------------
extern "C" void kernel_launch(void* const* d_in, const int* in_sizes, int n_in,
                              void* d_out, int out_size, void* d_ws, size_t ws_size,
                              hipStream_t stream)
{
    (void)in_sizes; (void)n_in; (void)out_size; (void)ws_size;
    const float* x    = (const float*)d_in[0];
    const float* Wp   = (const float*)d_in[1];
    const float* bp   = (const float*)d_in[2];
    const float* cls  = (const float*)d_in[3];
    const float* pos  = (const float*)d_in[4];
    const float* Wbb  = (const float*)d_in[5];
    const float* bbb  = (const float*)d_in[6];
    const float* Wqkv = (const float*)d_in[7];
    const float* bqkv = (const float*)d_in[8];
    const float* Wo   = (const float*)d_in[9];
    const float* bo   = (const float*)d_in[10];
    const float* ln1s = (const float*)d_in[11];
    const float* ln1b = (const float*)d_in[12];
    const float* W1   = (const float*)d_in[13];
    const float* b1   = (const float*)d_in[14];
    const float* W2   = (const float*)d_in[15];
    const float* b2   = (const float*)d_in[16];
    const float* ln2s = (const float*)d_in[17];
    const float* ln2b = (const float*)d_in[18];
    const float* lnfs = (const float*)d_in[19];
    const float* lnfb = (const float*)d_in[20];
    const float* Wh1  = (const float*)d_in[21];
    const float* bh1  = (const float*)d_in[22];
    const float* Wh2  = (const float*)d_in[23];
    const float* bh2  = (const float*)d_in[24];
    float* out = (float*)d_out;

    float* ws = (float*)d_ws;
    size_t off = 0;
    float* hbuf   = ws + off; off += (size_t)MROWS * E_;
    float* qslab  = ws + off; off += (size_t)3 * MPAD * E_;        // qkv bf16 / split-K partials / head part
    unsigned short* hbf  = (unsigned short*)(ws + off); off += (size_t)MPAD * E_ / 2;
    unsigned short* obf  = (unsigned short*)(ws + off); off += (size_t)MPAD * E_ / 2;
    unsigned short* ffbf = (unsigned short*)(ws + off); off += (size_t)MPAD * DFF_ / 2;  // also Pmbf
    unsigned short* wqb  = (unsigned short*)(ws + off); off += (size_t)L_ * WQKV_SZ / 2;
    unsigned short* wob  = (unsigned short*)(ws + off); off += (size_t)L_ * WO_SZ / 2;
    unsigned short* w1b  = (unsigned short*)(ws + off); off += (size_t)L_ * W1_SZ / 2;
    unsigned short* w2b  = (unsigned short*)(ws + off); off += (size_t)L_ * W2_SZ / 2;
    unsigned short* wpb  = (unsigned short*)(ws + off); off += (size_t)E_ * 3072 / 2;
    unsigned short* hfb  = (unsigned short*)(ws + off); off += (size_t)MROWS * E_ / 2;
    float* ximg  = ws + off; off += B_ * E_;
    float* xmean = ws + off; off += 128;
    float* out1  = ws + off; off += B_ * MLP_;

    float* part = qslab;
    unsigned short* qkvb = (unsigned short*)qslab;
    unsigned short* Pmbf = ffbf;

    // upfront: convert ALL weights to bf16 (pure streaming)
    cvt_kernel<<<(L_ * WQKV_SZ / 4 + 255) / 256, 256, 0, stream>>>(Wqkv, wqb, L_ * WQKV_SZ / 4);
    cvt_kernel<<<(L_ * WO_SZ / 4 + 255) / 256, 256, 0, stream>>>(Wo, wob, L_ * WO_SZ / 4);
    cvt_kernel<<<(L_ * W1_SZ / 4 + 255) / 256, 256, 0, stream>>>(W1, w1b, L_ * W1_SZ / 4);
    cvt_kernel<<<(L_ * W2_SZ / 4 + 255) / 256, 256, 0, stream>>>(W2, w2b, L_ * W2_SZ / 4);
    cvt_kernel<<<(E_ * 3072 / 4 + 255) / 256, 256, 0, stream>>>(Wp, wpb, E_ * 3072 / 4);

    // backbone token
    mean_kernel<<<B_ * C_, 256, 0, stream>>>(x, xmean);
    ximg_kernel<<<(B_ * E_ + 255) / 256, 256, 0, stream>>>(xmean, Wbb, bbb, ximg);

    // patch embedding
    im2col_kernel<<<(PMROWS * 3072 + 255) / 256, 256, 0, stream>>>(x, Pmbf);
    gemm_mfma<<<dim3(E_ / 128, PMPAD / 128, 3), 256, 0, stream>>>(
        Pmbf, wpb, nullptr, nullptr, nullptr, part, PMPAD, E_, 3072, 1024, 0);
    build_h0_kernel<<<(MROWS * E_ + 255) / 256, 256, 0, stream>>>(part, bp, cls, pos, hbuf, hbf);

    for (int i = 0; i < L_; ++i) {
        int start = 12 - i;
        // qkv: bf16 out
        gemm_mfma<<<dim3(2304 / 128, MPAD / 128, 1), 256, 0, stream>>>(
            hbf, wqb + (size_t)i * WQKV_SZ, bqkv + i * 2304, nullptr, qkvb, nullptr, MPAD, 2304, E_, E_, 0);
        attn_mfma<<<dim3(NH_, B_), 256, 0, stream>>>(qkvb, obf, start);
        // proj: split-K=3 partials (aliases qslab; qkvb already consumed)
        gemm_mfma<<<dim3(E_ / 128, MPAD / 128, 3), 256, 0, stream>>>(
            obf, wob + (size_t)i * WO_SZ, nullptr, nullptr, nullptr, part, MPAD, E_, E_, 256, 0);
        add_ln_fused<<<MROWS, 256, 0, stream>>>(
            hbuf, part, 3, bo + i * E_, ln1s + i * E_, ln1b + i * E_, hbuf, hbf, nullptr, -1);
        // ffn1: direct bf16 out + relu
        gemm_mfma<<<dim3(DFF_ / 128, MPAD / 128, 1), 256, 0, stream>>>(
            hbf, w1b + (size_t)i * W1_SZ, b1 + i * DFF_, nullptr, ffbf, nullptr, MPAD, DFF_, E_, E_, 1);
        // ffn2: split-K=3 partials
        gemm_mfma<<<dim3(E_ / 128, MPAD / 128, 3), 256, 0, stream>>>(
            ffbf, w2b + (size_t)i * W2_SZ, nullptr, nullptr, nullptr, part, MPAD, E_, DFF_, 1024, 0);
        add_ln_fused<<<MROWS, 256, 0, stream>>>(
            hbuf, part, 3, b2 + i * E_, ln2s + i * E_, ln2b + i * E_, hbuf, hbf, ximg, 11 - i);
    }

    // final LN (bf16 only) + head
    add_ln_fused<<<MROWS, 256, 0, stream>>>(
        hbuf, nullptr, 0, nullptr, lnfs, lnfb, nullptr, hfb, nullptr, -1);
    head1_mfma<<<dim3(MLP_ / 64, HKS), 256, 0, stream>>>(hfb, Wh1, part);
    head1_fin_kernel<<<(B_ * MLP_ + 255) / 256, 256, 0, stream>>>(part, bh1, out1);
    head2_kernel<<<B_ * NC_, 256, 0, stream>>>(out1, Wh2, bh2, out);
}